// Round 11
// baseline (80.384 us; speedup 1.0000x reference)
//
#include <hip/hip_runtime.h>
#include <math.h>

typedef _Float16 half8 __attribute__((ext_vector_type(8)));
typedef _Float16 half4v __attribute__((ext_vector_type(4)));
typedef float    f32x4 __attribute__((ext_vector_type(4)));

// ---------------- output offsets (floats) ----------------
#define O_Q     0
#define O_LOSS  2097152
#define O_IDX   2097153
#define O_PERP  2129921
#define O_NECS  2129922
#define O_EMAW  2130946
#define O_W     2196482

// ---------------- workspace offsets (4-byte units) ----------------
#define W_WBF    0          // 65536 fl (=131072 halfs): B-fragments [64ct][4j][64l][8e]
#define W_SW2    65536      // 1024  wsq  (fl32 of fp64 sum)
#define W_RSQ    66560      // 32768 rsq  (fl32 of fp64 sum)
#define W_IDX    99328      // 32768 int
#define W_CNT    132096     // 1024  counts
#define W_DW     133120     // 65536 dw
#define W_LOSS   198656     // 1     loss
#define W_ZN     66561      // floats to zero starting at W_CNT

#define F16_MIN_NORM 6.103515625e-05f   // 2^-14

// =====================================================================
// kernel 0 (prep, grid 256): unchanged from round 10 (verified)
// =====================================================================
__global__ __launch_bounds__(256)
void k_prep(const float* __restrict__ w, const float* __restrict__ x,
            _Float16* __restrict__ wbf, float* __restrict__ wsq,
            float* __restrict__ rsq, float* __restrict__ zbase) {
    __shared__ float sh[64][65];
    int tid = threadIdx.x, blk = blockIdx.x;

    for (int z = blk * 256 + tid; z < W_ZN; z += 256 * 256) zbase[z] = 0.f;

    if (blk < 64) {
        int T  = blk * 256 + tid;           // 0..16383
        int ct = T >> 8, j = (T >> 6) & 3, l = T & 63;
        int kb = j & 1, isLo = j >> 1;
        int c  = ct * 16 + (l & 15), g = l >> 4;
        half8 o;
        #pragma unroll
        for (int e = 0; e < 8; ++e) {
            int kd = kb * 32 + g * 4 + (e & 3) + ((e >> 2) << 4);
            float wv = w[c * 64 + kd];
            _Float16 h = (fabsf(wv) >= F16_MIN_NORM) ? (_Float16)wv : (_Float16)0.f;
            if (isLo) {
                float hf = (float)h;
                o[e] = (_Float16)((wv - hf) * 16384.0f);   // lo scaled 2^14
            } else {
                o[e] = h;
            }
        }
        *(half8*)(wbf + ((ct * 4 + j) * 64 + l) * 8) = o;
    }

    if (blk < 16) {           // wsq
        int j0 = blk * 64;
        for (int p = 0; p < 16; ++p) {
            int f = p * 256 + tid;
            int j = f >> 6, d = f & 63;
            sh[j][d] = w[(j0 + j) * 64 + d];
        }
        __syncthreads();
        if (tid < 64) {
            double s = 0.0;
            #pragma unroll
            for (int d = 0; d < 64; ++d) {
                double v = (double)sh[tid][d];
                s = fma(v, v, s);
            }
            wsq[j0 + tid] = (float)s;
        }
    }

    if (blk >= 128) {         // rsq, one row per thread, d ascending
        int r = (blk - 128) * 256 + tid;
        const float* xp = x + (r >> 10) * 65536 + (r & 1023);
        double s = 0.0;
        #pragma unroll 8
        for (int d = 0; d < 64; ++d) {
            double v = (double)xp[d * 1024];
            s = fma(v, v, s);
        }
        rsq[r] = (float)s;
    }
}

// =====================================================================
// kernel 1: MFMA distances + argmin — 1-wave blocks, 32 rows/wave.
// grid 1024 x 64 thr; wave holds A-frags for 2 row-tiles in registers,
// streams all 64 code-tiles (each B-load now feeds 12 MFMAs, halving
// L1 traffic vs round 10; 16 waves/CU occupancy target).
// Numerics bitwise-identical to round-10 PASSING kernel (same wbf, same
// A conversion, same MFMA order c1/c2/c3, same epilogue fma sequence,
// ct-ascending scan, tie -> lowest code index).
// =====================================================================
__global__ __launch_bounds__(64, 4)
void k_dist(const float* __restrict__ x, const _Float16* __restrict__ wbf,
            const float* __restrict__ wsq, const float* __restrict__ rsq_g,
            int* __restrict__ idx_int, float* __restrict__ out_idxf) {
    __shared__ _Float16 xhi[64 * 32];
    __shared__ _Float16 xlo[64 * 32];
    int tid = threadIdx.x;
    int rbase = blockIdx.x * 32;
    int b = rbase >> 10, hw0 = rbase & 1023;
    const float* xb = x + b * 65536 + hw0;

    // stage 32 rows -> f16 hi/lo (xlo scaled 2^11)
    #pragma unroll
    for (int p = 0; p < 8; ++p) {
        int f = p * 64 + tid;
        int d = f >> 3, r4 = (f & 7) << 2;
        float4 v = *(const float4*)(xb + d * 1024 + r4);
        float vv[4] = {v.x, v.y, v.z, v.w};
        half4v h, lo;
        #pragma unroll
        for (int q = 0; q < 4; ++q) {
            float xv = vv[q];
            _Float16 hh = (fabsf(xv) >= F16_MIN_NORM) ? (_Float16)xv : (_Float16)0.f;
            h[q]  = hh;
            lo[q] = (_Float16)((xv - (float)hh) * 2048.0f);
        }
        *(half4v*)&xhi[d * 32 + r4] = h;
        *(half4v*)&xlo[d * 32 + r4] = lo;
    }
    __syncthreads();

    int l = tid & 63;
    int g = l >> 4, n16 = l & 15;

    // A fragments for both row-tiles (resident whole kernel)
    half8 ahi[2][2], alo[2][2];
    #pragma unroll
    for (int t = 0; t < 2; ++t)
        #pragma unroll
        for (int kb = 0; kb < 2; ++kb) {
            #pragma unroll
            for (int e = 0; e < 8; ++e) {
                int kd = kb * 32 + g * 4 + (e & 3) + ((e >> 2) << 4);
                ahi[t][kb][e] = xhi[kd * 32 + t * 16 + n16];
                alo[t][kb][e] = xlo[kd * 32 + t * 16 + n16];
            }
        }

    float rq[2][4];
    #pragma unroll
    for (int t = 0; t < 2; ++t)
        #pragma unroll
        for (int i = 0; i < 4; ++i)
            rq[t][i] = rsq_g[rbase + t * 16 + g * 4 + i];

    float best[2][4];
    int   bidx[2][4];
    #pragma unroll
    for (int t = 0; t < 2; ++t)
        #pragma unroll
        for (int i = 0; i < 4; ++i) { best[t][i] = 3.4e38f; bidx[t][i] = 0; }

    const half8* wv8 = (const half8*)wbf;
    #pragma unroll 1
    for (int ct = 0; ct < 64; ++ct) {
        const half8* wb = wv8 + ct * 256 + l;
        half8 bh0 = wb[0], bh1 = wb[64], bl0 = wb[128], bl1 = wb[192];
        float wsqv = wsq[ct * 16 + n16];
        int n = ct * 16 + n16;

        #pragma unroll
        for (int t = 0; t < 2; ++t) {
            f32x4 c1 = {0.f, 0.f, 0.f, 0.f};
            f32x4 c2 = {0.f, 0.f, 0.f, 0.f};
            f32x4 c3 = {0.f, 0.f, 0.f, 0.f};
            c1 = __builtin_amdgcn_mfma_f32_16x16x32_f16(ahi[t][0], bh0, c1, 0, 0, 0);
            c1 = __builtin_amdgcn_mfma_f32_16x16x32_f16(ahi[t][1], bh1, c1, 0, 0, 0);
            c2 = __builtin_amdgcn_mfma_f32_16x16x32_f16(alo[t][0], bh0, c2, 0, 0, 0);
            c2 = __builtin_amdgcn_mfma_f32_16x16x32_f16(alo[t][1], bh1, c2, 0, 0, 0);
            c3 = __builtin_amdgcn_mfma_f32_16x16x32_f16(ahi[t][0], bl0, c3, 0, 0, 0);
            c3 = __builtin_amdgcn_mfma_f32_16x16x32_f16(ahi[t][1], bl1, c3, 0, 0, 0);

            #pragma unroll
            for (int i = 0; i < 4; ++i) {
                float dot = fmaf(c2[i], 4.8828125e-4f, c1[i]);      // +C2*2^-11
                dot = fmaf(c3[i], 6.103515625e-05f, dot);           // +C3*2^-14
                float t1 = rq[t][i] + wsqv;                         // fl32 add @ ~64
                float sc = fmaf(dot, -2.0f, t1);                    // one rounding
                if (sc < best[t][i]) { best[t][i] = sc; bidx[t][i] = n; }
            }
        }
    }

    // reduce across the 16 lanes of each group (tie -> lower index)
    #pragma unroll
    for (int off = 1; off < 16; off <<= 1) {
        #pragma unroll
        for (int t = 0; t < 2; ++t)
            #pragma unroll
            for (int i = 0; i < 4; ++i) {
                float ov = __shfl_xor(best[t][i], off);
                int   oi = __shfl_xor(bidx[t][i], off);
                if (ov < best[t][i] || (ov == best[t][i] && oi < bidx[t][i])) {
                    best[t][i] = ov; bidx[t][i] = oi;
                }
            }
    }
    if (n16 == 0) {
        #pragma unroll
        for (int t = 0; t < 2; ++t)
            #pragma unroll
            for (int i = 0; i < 4; ++i) {
                int r = rbase + t * 16 + g * 4 + i;
                idx_int[r]  = bidx[t][i];
                out_idxf[r] = (float)bidx[t][i];
            }
    }
}

// =====================================================================
// kernel 2: quantized output + loss + counts + dw (round-4-verified)
// =====================================================================
__global__ __launch_bounds__(256)
void k_quant(const float* __restrict__ x, const float* __restrict__ w,
             const int* __restrict__ idx_int, float* __restrict__ outq,
             float* __restrict__ counts, float* __restrict__ dw,
             float* __restrict__ loss) {
    __shared__ float xs[64][65];
    __shared__ int   idxl[64];
    __shared__ float red[4];
    int tid = threadIdx.x;
    int n0  = blockIdx.x * 64;
    int b   = n0 >> 10, hw0 = n0 & 1023;
    const float* xb = x + b * 65536 + hw0;

    if (tid < 64) {
        int id = idx_int[n0 + tid];
        idxl[tid] = id;
        atomicAdd(&counts[id], 1.0f);
    }
    for (int p = 0; p < 16; ++p) {
        int f = p * 256 + tid;
        int d = f >> 6, n = f & 63;
        xs[d][n] = xb[d * 1024 + n];
    }
    __syncthreads();

    float ll = 0.f;
    for (int p = 0; p < 16; ++p) {
        int f = p * 256 + tid;
        int d = f >> 6, n = f & 63;
        float q  = w[idxl[n] * 64 + d];
        float xv = xs[d][n];
        float dd = q - xv;
        ll += dd * dd;
        outq[b * 65536 + d * 1024 + hw0 + n] = q;
    }
    #pragma unroll
    for (int off = 32; off; off >>= 1) ll += __shfl_down(ll, off);
    if ((tid & 63) == 0) red[tid >> 6] = ll;
    __syncthreads();
    if (tid == 0) atomicAdd(loss, red[0] + red[1] + red[2] + red[3]);

    int wv = tid >> 6, lane = tid & 63;
    for (int v = 0; v < 16; ++v) {
        int n = wv * 16 + v;
        atomicAdd(&dw[idxl[n] * 64 + lane], xs[lane][n]);
    }
}

// =====================================================================
// kernel 3 (merged finalize, round-9-verified)
// =====================================================================
__global__ __launch_bounds__(256)
void k_final(const float* __restrict__ ema_cs, const float* __restrict__ ema_w,
             const float* __restrict__ counts, const float* __restrict__ dw,
             const float* __restrict__ loss, float* __restrict__ out) {
    __shared__ float cs[1024];
    __shared__ float redA[4], redB[4];
    int tid = threadIdx.x;

    float necs[4];
    float s1 = 0.f, s2 = 0.f;
    #pragma unroll
    for (int q = 0; q < 4; ++q) {
        int j = q * 256 + tid;
        float c  = counts[j];
        float ne = 0.99f * ema_cs[j] + 0.01f * c;
        necs[q] = ne;
        float p = c * (1.0f / 32768.0f);
        s1 += ne;
        s2 += -p * logf(p + 1e-10f);
    }
    #pragma unroll
    for (int off = 32; off; off >>= 1) {
        s1 += __shfl_down(s1, off);
        s2 += __shfl_down(s2, off);
    }
    if ((tid & 63) == 0) { redA[tid >> 6] = s1; redB[tid >> 6] = s2; }
    __syncthreads();
    float ntot = redA[0] + redA[1] + redA[2] + redA[3];
    #pragma unroll
    for (int q = 0; q < 4; ++q)
        cs[q * 256 + tid] = (necs[q] + 1e-5f) / (ntot + 1024.0f * 1e-5f) * ntot;

    if (blockIdx.x == 0) {
        #pragma unroll
        for (int q = 0; q < 4; ++q) out[O_NECS + q * 256 + tid] = necs[q];
        if (tid == 0) {
            out[O_PERP] = expf(redB[0] + redB[1] + redB[2] + redB[3]);
            out[O_LOSS] = 0.25f * loss[0] * (1.0f / 2097152.0f);
        }
    }
    __syncthreads();

    int f = blockIdx.x * 256 + tid;
    int j = f >> 6;
    float ne = 0.99f * ema_w[f] + 0.01f * dw[f];
    out[O_EMAW + f] = ne;
    out[O_W + f]    = ne / cs[j];
}

// =====================================================================
extern "C" void kernel_launch(void* const* d_in, const int* in_sizes, int n_in,
                              void* d_out, int out_size, void* d_ws, size_t ws_size,
                              hipStream_t stream) {
    const float* x      = (const float*)d_in[0];
    const float* w      = (const float*)d_in[1];
    const float* ema_cs = (const float*)d_in[2];
    const float* ema_w  = (const float*)d_in[3];
    float* out = (float*)d_out;
    float* ws  = (float*)d_ws;

    _Float16* wbf  = (_Float16*)(ws + W_WBF);
    float* wsq     = ws + W_SW2;
    float* rsqb    = ws + W_RSQ;
    int*   idxi    = (int*)(ws + W_IDX);
    float* counts  = ws + W_CNT;
    float* dwb     = ws + W_DW;
    float* lossb   = ws + W_LOSS;

    k_prep <<<256,  256, 0, stream>>>(w, x, wbf, wsq, rsqb, counts);
    k_dist <<<1024,  64, 0, stream>>>(x, wbf, wsq, rsqb, idxi, out + O_IDX);
    k_quant<<<512,  256, 0, stream>>>(x, w, idxi, out + O_Q, counts, dwb, lossb);
    k_final<<<256,  256, 0, stream>>>(ema_cs, ema_w, counts, dwb, lossb, out);
}

// Round 12
// 54.782 us; speedup vs baseline: 1.4674x; 1.4674x over previous
//
#include <hip/hip_runtime.h>
#include <math.h>

typedef _Float16 half8 __attribute__((ext_vector_type(8)));
typedef _Float16 half4v __attribute__((ext_vector_type(4)));
typedef float    f32x4 __attribute__((ext_vector_type(4)));

// ---------------- output offsets (floats) ----------------
#define O_Q     0
#define O_LOSS  2097152
#define O_IDX   2097153
#define O_PERP  2129921
#define O_NECS  2129922
#define O_EMAW  2130946
#define O_W     2196482

// ---------------- workspace offsets (4-byte units) ----------------
#define W_WBF    0          // 65536 fl (=131072 halfs): B-fragments [64ct][4j][64l][8e]
#define W_SW2    65536      // 1024  wsq  (fl32 of fp64 sum)
#define W_RSQ    66560      // 32768 rsq  (fl32 of fp64 sum)
#define W_IDX    99328      // 32768 int
#define W_CNT    132096     // 1024  counts
#define W_DW     133120     // 65536 dw
#define W_LOSS   198656     // 1     loss
#define W_ZN     66561      // floats to zero starting at W_CNT

#define F16_MIN_NORM 6.103515625e-05f   // 2^-14

// =====================================================================
// kernel 0 (prep, grid 256): unchanged from round 10 (verified)
// =====================================================================
__global__ __launch_bounds__(256)
void k_prep(const float* __restrict__ w, const float* __restrict__ x,
            _Float16* __restrict__ wbf, float* __restrict__ wsq,
            float* __restrict__ rsq, float* __restrict__ zbase) {
    __shared__ float sh[64][65];
    int tid = threadIdx.x, blk = blockIdx.x;

    for (int z = blk * 256 + tid; z < W_ZN; z += 256 * 256) zbase[z] = 0.f;

    if (blk < 64) {
        int T  = blk * 256 + tid;           // 0..16383
        int ct = T >> 8, j = (T >> 6) & 3, l = T & 63;
        int kb = j & 1, isLo = j >> 1;
        int c  = ct * 16 + (l & 15), g = l >> 4;
        half8 o;
        #pragma unroll
        for (int e = 0; e < 8; ++e) {
            int kd = kb * 32 + g * 4 + (e & 3) + ((e >> 2) << 4);
            float wv = w[c * 64 + kd];
            _Float16 h = (fabsf(wv) >= F16_MIN_NORM) ? (_Float16)wv : (_Float16)0.f;
            if (isLo) {
                float hf = (float)h;
                o[e] = (_Float16)((wv - hf) * 16384.0f);   // lo scaled 2^14
            } else {
                o[e] = h;
            }
        }
        *(half8*)(wbf + ((ct * 4 + j) * 64 + l) * 8) = o;
    }

    if (blk < 16) {           // wsq
        int j0 = blk * 64;
        for (int p = 0; p < 16; ++p) {
            int f = p * 256 + tid;
            int j = f >> 6, d = f & 63;
            sh[j][d] = w[(j0 + j) * 64 + d];
        }
        __syncthreads();
        if (tid < 64) {
            double s = 0.0;
            #pragma unroll
            for (int d = 0; d < 64; ++d) {
                double v = (double)sh[tid][d];
                s = fma(v, v, s);
            }
            wsq[j0 + tid] = (float)s;
        }
    }

    if (blk >= 128) {         // rsq, one row per thread, d ascending
        int r = (blk - 128) * 256 + tid;
        const float* xp = x + (r >> 10) * 65536 + (r & 1023);
        double s = 0.0;
        #pragma unroll 8
        for (int d = 0; d < 64; ++d) {
            double v = (double)xp[d * 1024];
            s = fma(v, v, s);
        }
        rsq[r] = (float)s;
    }
}

// =====================================================================
// kernel 1: MFMA distances + argmin — ct-split waves for occupancy.
// grid 1024 x 256 thr (4 waves): wave = (row-tile rt in {0,1}) x
// (ct-half ch in {0,1}); block covers 32 rows; each wave scans 32
// code-tiles. 4096 waves total = 16 waves/CU = 4/SIMD. In-block merge
// of the two ct-halves prefers half 0 on ties == global ct-ascending
// first-min. Per-(row,ct) numerics bitwise-identical to rounds 10/11
// (same wbf, A conversion, c1/c2/c3 MFMA order, epilogue fma chain).
// =====================================================================
__global__ __launch_bounds__(256, 4)
void k_dist(const float* __restrict__ x, const _Float16* __restrict__ wbf,
            const float* __restrict__ wsq, const float* __restrict__ rsq_g,
            int* __restrict__ idx_int, float* __restrict__ out_idxf) {
    __shared__ _Float16 xhi[64 * 32];
    __shared__ _Float16 xlo[64 * 32];
    __shared__ float bvs[2][32];
    __shared__ int   bis[2][32];
    int tid = threadIdx.x;
    int rbase = blockIdx.x * 32;
    int b = rbase >> 10, hw0 = rbase & 1023;
    const float* xb = x + b * 65536 + hw0;

    // stage 32 rows -> f16 hi/lo (xlo scaled 2^11)
    #pragma unroll
    for (int p = 0; p < 2; ++p) {
        int f = p * 256 + tid;
        int d = f >> 3, r4 = (f & 7) << 2;
        float4 v = *(const float4*)(xb + d * 1024 + r4);
        float vv[4] = {v.x, v.y, v.z, v.w};
        half4v h, lo;
        #pragma unroll
        for (int q = 0; q < 4; ++q) {
            float xv = vv[q];
            _Float16 hh = (fabsf(xv) >= F16_MIN_NORM) ? (_Float16)xv : (_Float16)0.f;
            h[q]  = hh;
            lo[q] = (_Float16)((xv - (float)hh) * 2048.0f);
        }
        *(half4v*)&xhi[d * 32 + r4] = h;
        *(half4v*)&xlo[d * 32 + r4] = lo;
    }
    __syncthreads();

    int l   = tid & 63;
    int wid = tid >> 6;
    int rt  = wid & 1;          // row-tile of this wave
    int ch  = wid >> 1;         // ct-half of this wave
    int g = l >> 4, n16 = l & 15;
    int m = rt * 16 + n16;

    // A fragments for this wave's row-tile
    half8 ahi[2], alo[2];
    #pragma unroll
    for (int kb = 0; kb < 2; ++kb) {
        #pragma unroll
        for (int e = 0; e < 8; ++e) {
            int kd = kb * 32 + g * 4 + (e & 3) + ((e >> 2) << 4);
            ahi[kb][e] = xhi[kd * 32 + m];
            alo[kb][e] = xlo[kd * 32 + m];
        }
    }

    float rq[4];
    #pragma unroll
    for (int i = 0; i < 4; ++i) rq[i] = rsq_g[rbase + rt * 16 + g * 4 + i];

    float best[4];
    int   bidx[4];
    #pragma unroll
    for (int i = 0; i < 4; ++i) { best[i] = 3.4e38f; bidx[i] = 0; }

    const half8* wv8 = (const half8*)wbf;
    #pragma unroll 2
    for (int c8 = 0; c8 < 32; ++c8) {
        int ct = ch * 32 + c8;
        const half8* wb = wv8 + ct * 256 + l;
        half8 bh0 = wb[0], bh1 = wb[64], bl0 = wb[128], bl1 = wb[192];

        f32x4 c1 = {0.f, 0.f, 0.f, 0.f};
        f32x4 c2 = {0.f, 0.f, 0.f, 0.f};
        f32x4 c3 = {0.f, 0.f, 0.f, 0.f};
        c1 = __builtin_amdgcn_mfma_f32_16x16x32_f16(ahi[0], bh0, c1, 0, 0, 0);
        c1 = __builtin_amdgcn_mfma_f32_16x16x32_f16(ahi[1], bh1, c1, 0, 0, 0);
        c2 = __builtin_amdgcn_mfma_f32_16x16x32_f16(alo[0], bh0, c2, 0, 0, 0);
        c2 = __builtin_amdgcn_mfma_f32_16x16x32_f16(alo[1], bh1, c2, 0, 0, 0);
        c3 = __builtin_amdgcn_mfma_f32_16x16x32_f16(ahi[0], bl0, c3, 0, 0, 0);
        c3 = __builtin_amdgcn_mfma_f32_16x16x32_f16(ahi[1], bl1, c3, 0, 0, 0);

        float wsqv = wsq[ct * 16 + n16];
        int n = ct * 16 + n16;
        #pragma unroll
        for (int i = 0; i < 4; ++i) {
            float dot = fmaf(c2[i], 4.8828125e-4f, c1[i]);      // +C2*2^-11
            dot = fmaf(c3[i], 6.103515625e-05f, dot);           // +C3*2^-14
            float t1 = rq[i] + wsqv;                            // fl32 add @ ~64
            float sc = fmaf(dot, -2.0f, t1);                    // one rounding
            if (sc < best[i]) { best[i] = sc; bidx[i] = n; }    // ct asc => first-min
        }
    }

    // reduce across the 16 lanes of each group (tie -> lower index)
    #pragma unroll
    for (int off = 1; off < 16; off <<= 1) {
        #pragma unroll
        for (int i = 0; i < 4; ++i) {
            float ov = __shfl_xor(best[i], off);
            int   oi = __shfl_xor(bidx[i], off);
            if (ov < best[i] || (ov == best[i] && oi < bidx[i])) {
                best[i] = ov; bidx[i] = oi;
            }
        }
    }
    if (n16 == 0) {
        #pragma unroll
        for (int i = 0; i < 4; ++i) {
            bvs[ch][rt * 16 + g * 4 + i] = best[i];
            bis[ch][rt * 16 + g * 4 + i] = bidx[i];
        }
    }
    __syncthreads();

    // merge ct-halves; strict < with half-0 default keeps lowest code index
    if (tid < 32) {
        float b0 = bvs[0][tid]; int i0 = bis[0][tid];
        float b1 = bvs[1][tid]; int i1 = bis[1][tid];
        int ii = (b1 < b0) ? i1 : i0;
        idx_int[rbase + tid]  = ii;
        out_idxf[rbase + tid] = (float)ii;
    }
}

// =====================================================================
// kernel 2: quantized output + loss + counts + dw (round-4-verified)
// =====================================================================
__global__ __launch_bounds__(256)
void k_quant(const float* __restrict__ x, const float* __restrict__ w,
             const int* __restrict__ idx_int, float* __restrict__ outq,
             float* __restrict__ counts, float* __restrict__ dw,
             float* __restrict__ loss) {
    __shared__ float xs[64][65];
    __shared__ int   idxl[64];
    __shared__ float red[4];
    int tid = threadIdx.x;
    int n0  = blockIdx.x * 64;
    int b   = n0 >> 10, hw0 = n0 & 1023;
    const float* xb = x + b * 65536 + hw0;

    if (tid < 64) {
        int id = idx_int[n0 + tid];
        idxl[tid] = id;
        atomicAdd(&counts[id], 1.0f);
    }
    for (int p = 0; p < 16; ++p) {
        int f = p * 256 + tid;
        int d = f >> 6, n = f & 63;
        xs[d][n] = xb[d * 1024 + n];
    }
    __syncthreads();

    float ll = 0.f;
    for (int p = 0; p < 16; ++p) {
        int f = p * 256 + tid;
        int d = f >> 6, n = f & 63;
        float q  = w[idxl[n] * 64 + d];
        float xv = xs[d][n];
        float dd = q - xv;
        ll += dd * dd;
        outq[b * 65536 + d * 1024 + hw0 + n] = q;
    }
    #pragma unroll
    for (int off = 32; off; off >>= 1) ll += __shfl_down(ll, off);
    if ((tid & 63) == 0) red[tid >> 6] = ll;
    __syncthreads();
    if (tid == 0) atomicAdd(loss, red[0] + red[1] + red[2] + red[3]);

    int wv = tid >> 6, lane = tid & 63;
    for (int v = 0; v < 16; ++v) {
        int n = wv * 16 + v;
        atomicAdd(&dw[idxl[n] * 64 + lane], xs[lane][n]);
    }
}

// =====================================================================
// kernel 3 (merged finalize, round-9-verified)
// =====================================================================
__global__ __launch_bounds__(256)
void k_final(const float* __restrict__ ema_cs, const float* __restrict__ ema_w,
             const float* __restrict__ counts, const float* __restrict__ dw,
             const float* __restrict__ loss, float* __restrict__ out) {
    __shared__ float cs[1024];
    __shared__ float redA[4], redB[4];
    int tid = threadIdx.x;

    float necs[4];
    float s1 = 0.f, s2 = 0.f;
    #pragma unroll
    for (int q = 0; q < 4; ++q) {
        int j = q * 256 + tid;
        float c  = counts[j];
        float ne = 0.99f * ema_cs[j] + 0.01f * c;
        necs[q] = ne;
        float p = c * (1.0f / 32768.0f);
        s1 += ne;
        s2 += -p * logf(p + 1e-10f);
    }
    #pragma unroll
    for (int off = 32; off; off >>= 1) {
        s1 += __shfl_down(s1, off);
        s2 += __shfl_down(s2, off);
    }
    if ((tid & 63) == 0) { redA[tid >> 6] = s1; redB[tid >> 6] = s2; }
    __syncthreads();
    float ntot = redA[0] + redA[1] + redA[2] + redA[3];
    #pragma unroll
    for (int q = 0; q < 4; ++q)
        cs[q * 256 + tid] = (necs[q] + 1e-5f) / (ntot + 1024.0f * 1e-5f) * ntot;

    if (blockIdx.x == 0) {
        #pragma unroll
        for (int q = 0; q < 4; ++q) out[O_NECS + q * 256 + tid] = necs[q];
        if (tid == 0) {
            out[O_PERP] = expf(redB[0] + redB[1] + redB[2] + redB[3]);
            out[O_LOSS] = 0.25f * loss[0] * (1.0f / 2097152.0f);
        }
    }
    __syncthreads();

    int f = blockIdx.x * 256 + tid;
    int j = f >> 6;
    float ne = 0.99f * ema_w[f] + 0.01f * dw[f];
    out[O_EMAW + f] = ne;
    out[O_W + f]    = ne / cs[j];
}

// =====================================================================
extern "C" void kernel_launch(void* const* d_in, const int* in_sizes, int n_in,
                              void* d_out, int out_size, void* d_ws, size_t ws_size,
                              hipStream_t stream) {
    const float* x      = (const float*)d_in[0];
    const float* w      = (const float*)d_in[1];
    const float* ema_cs = (const float*)d_in[2];
    const float* ema_w  = (const float*)d_in[3];
    float* out = (float*)d_out;
    float* ws  = (float*)d_ws;

    _Float16* wbf  = (_Float16*)(ws + W_WBF);
    float* wsq     = ws + W_SW2;
    float* rsqb    = ws + W_RSQ;
    int*   idxi    = (int*)(ws + W_IDX);
    float* counts  = ws + W_CNT;
    float* dwb     = ws + W_DW;
    float* lossb   = ws + W_LOSS;

    k_prep <<<256,  256, 0, stream>>>(w, x, wbf, wsq, rsqb, counts);
    k_dist <<<1024, 256, 0, stream>>>(x, wbf, wsq, rsqb, idxi, out + O_IDX);
    k_quant<<<512,  256, 0, stream>>>(x, w, idxi, out + O_Q, counts, dwb, lossb);
    k_final<<<256,  256, 0, stream>>>(ema_cs, ema_w, counts, dwb, lossb, out);
}

// Round 13
// 49.575 us; speedup vs baseline: 1.6215x; 1.1050x over previous
//
#include <hip/hip_runtime.h>
#include <math.h>

typedef _Float16 half8 __attribute__((ext_vector_type(8)));
typedef _Float16 half4v __attribute__((ext_vector_type(4)));
typedef float    f32x4 __attribute__((ext_vector_type(4)));

// ---------------- output offsets (floats) ----------------
#define O_Q     0
#define O_LOSS  2097152
#define O_IDX   2097153
#define O_PERP  2129921
#define O_NECS  2129922
#define O_EMAW  2130946
#define O_W     2196482

// ---------------- workspace offsets (4-byte units) ----------------
#define W_WBF    0          // 65536 fl (=131072 halfs): B-fragments [64ct][4j][64l][8e]
#define W_SW2    65536      // 1024  wsq  (fl32 of fp64 sum)
#define W_RSQ    66560      // 32768 rsq  (fl32 of fp64 sum)
#define W_CNT    132096     // 1024  counts
#define W_DW     133120     // 65536 dw
#define W_LOSS   198656     // 1     loss
#define W_ZN     66561      // floats to zero starting at W_CNT

#define F16_MIN_NORM 6.103515625e-05f   // 2^-14

// =====================================================================
// kernel 0 (prep, grid 256): unchanged from round 10 (verified)
// =====================================================================
__global__ __launch_bounds__(256)
void k_prep(const float* __restrict__ w, const float* __restrict__ x,
            _Float16* __restrict__ wbf, float* __restrict__ wsq,
            float* __restrict__ rsq, float* __restrict__ zbase) {
    __shared__ float sh[64][65];
    int tid = threadIdx.x, blk = blockIdx.x;

    for (int z = blk * 256 + tid; z < W_ZN; z += 256 * 256) zbase[z] = 0.f;

    if (blk < 64) {
        int T  = blk * 256 + tid;           // 0..16383
        int ct = T >> 8, j = (T >> 6) & 3, l = T & 63;
        int kb = j & 1, isLo = j >> 1;
        int c  = ct * 16 + (l & 15), g = l >> 4;
        half8 o;
        #pragma unroll
        for (int e = 0; e < 8; ++e) {
            int kd = kb * 32 + g * 4 + (e & 3) + ((e >> 2) << 4);
            float wv = w[c * 64 + kd];
            _Float16 h = (fabsf(wv) >= F16_MIN_NORM) ? (_Float16)wv : (_Float16)0.f;
            if (isLo) {
                float hf = (float)h;
                o[e] = (_Float16)((wv - hf) * 16384.0f);   // lo scaled 2^14
            } else {
                o[e] = h;
            }
        }
        *(half8*)(wbf + ((ct * 4 + j) * 64 + l) * 8) = o;
    }

    if (blk < 16) {           // wsq
        int j0 = blk * 64;
        for (int p = 0; p < 16; ++p) {
            int f = p * 256 + tid;
            int j = f >> 6, d = f & 63;
            sh[j][d] = w[(j0 + j) * 64 + d];
        }
        __syncthreads();
        if (tid < 64) {
            double s = 0.0;
            #pragma unroll
            for (int d = 0; d < 64; ++d) {
                double v = (double)sh[tid][d];
                s = fma(v, v, s);
            }
            wsq[j0 + tid] = (float)s;
        }
    }

    if (blk >= 128) {         // rsq, one row per thread, d ascending
        int r = (blk - 128) * 256 + tid;
        const float* xp = x + (r >> 10) * 65536 + (r & 1023);
        double s = 0.0;
        #pragma unroll 8
        for (int d = 0; d < 64; ++d) {
            double v = (double)xp[d * 1024];
            s = fma(v, v, s);
        }
        rsq[r] = (float)s;
    }
}

// =====================================================================
// kernel 1 (fused): MFMA distances + argmin + quant/loss/counts/dw.
// grid 1024 x 256 thr (4 waves). Block = 32 rows. Each wave owns a
// ct-QUARTER (16 cts) and computes BOTH row-tiles -> each B-load feeds
// 12 MFMAs (L1 B-traffic halved vs round 12); 16 waves/CU.
// 4-way ct-quarter merge (q ascending, strict <) == global ct-ascending
// first-min. Per-(row,ct) numerics bitwise-identical to rounds 10-12.
// Quant phase uses the round-4-verified access patterns on LDS x32.
// =====================================================================
__global__ __launch_bounds__(256, 4)
void k_dist(const float* __restrict__ x, const _Float16* __restrict__ wbf,
            const float* __restrict__ wsq, const float* __restrict__ rsq_g,
            const float* __restrict__ w,
            int* __restrict__ idx_out_unused, float* __restrict__ out_idxf,
            float* __restrict__ outq, float* __restrict__ counts,
            float* __restrict__ dw, float* __restrict__ loss) {
    __shared__ _Float16 xhi[64 * 32];
    __shared__ _Float16 xlo[64 * 32];
    __shared__ float x32[32][65];
    __shared__ float bvs[4][32];
    __shared__ int   bis[4][32];
    __shared__ int   idxl[32];
    __shared__ float red[4];
    int tid = threadIdx.x;
    int rbase = blockIdx.x * 32;
    int b = rbase >> 10, hw0 = rbase & 1023;
    const float* xb = x + b * 65536 + hw0;

    // stage 32 rows -> f16 hi/lo (xlo scaled 2^11) + fp32 copy
    #pragma unroll
    for (int p = 0; p < 2; ++p) {
        int f = p * 256 + tid;
        int d = f >> 3, r4 = (f & 7) << 2;
        float4 v = *(const float4*)(xb + d * 1024 + r4);
        float vv[4] = {v.x, v.y, v.z, v.w};
        half4v h, lo;
        #pragma unroll
        for (int q = 0; q < 4; ++q) {
            float xv = vv[q];
            _Float16 hh = (fabsf(xv) >= F16_MIN_NORM) ? (_Float16)xv : (_Float16)0.f;
            h[q]  = hh;
            lo[q] = (_Float16)((xv - (float)hh) * 2048.0f);
            x32[r4 + q][d] = xv;
        }
        *(half4v*)&xhi[d * 32 + r4] = h;
        *(half4v*)&xlo[d * 32 + r4] = lo;
    }
    __syncthreads();

    int l   = tid & 63;
    int wid = tid >> 6;          // ct-quarter of this wave
    int g = l >> 4, n16 = l & 15;

    // A fragments for BOTH row-tiles (resident for the whole ct loop)
    half8 ahi[2][2], alo[2][2];
    #pragma unroll
    for (int t = 0; t < 2; ++t)
        #pragma unroll
        for (int kb = 0; kb < 2; ++kb) {
            #pragma unroll
            for (int e = 0; e < 8; ++e) {
                int kd = kb * 32 + g * 4 + (e & 3) + ((e >> 2) << 4);
                ahi[t][kb][e] = xhi[kd * 32 + t * 16 + n16];
                alo[t][kb][e] = xlo[kd * 32 + t * 16 + n16];
            }
        }

    float rq[2][4];
    #pragma unroll
    for (int t = 0; t < 2; ++t)
        #pragma unroll
        for (int i = 0; i < 4; ++i)
            rq[t][i] = rsq_g[rbase + t * 16 + g * 4 + i];

    float best[2][4];
    int   bidx[2][4];
    #pragma unroll
    for (int t = 0; t < 2; ++t)
        #pragma unroll
        for (int i = 0; i < 4; ++i) { best[t][i] = 3.4e38f; bidx[t][i] = 0; }

    const half8* wv8 = (const half8*)wbf;
    #pragma unroll 2
    for (int c8 = 0; c8 < 16; ++c8) {
        int ct = wid * 16 + c8;
        const half8* wb = wv8 + ct * 256 + l;
        half8 bh0 = wb[0], bh1 = wb[64], bl0 = wb[128], bl1 = wb[192];
        float wsqv = wsq[ct * 16 + n16];
        int n = ct * 16 + n16;

        #pragma unroll
        for (int t = 0; t < 2; ++t) {
            f32x4 c1 = {0.f, 0.f, 0.f, 0.f};
            f32x4 c2 = {0.f, 0.f, 0.f, 0.f};
            f32x4 c3 = {0.f, 0.f, 0.f, 0.f};
            c1 = __builtin_amdgcn_mfma_f32_16x16x32_f16(ahi[t][0], bh0, c1, 0, 0, 0);
            c1 = __builtin_amdgcn_mfma_f32_16x16x32_f16(ahi[t][1], bh1, c1, 0, 0, 0);
            c2 = __builtin_amdgcn_mfma_f32_16x16x32_f16(alo[t][0], bh0, c2, 0, 0, 0);
            c2 = __builtin_amdgcn_mfma_f32_16x16x32_f16(alo[t][1], bh1, c2, 0, 0, 0);
            c3 = __builtin_amdgcn_mfma_f32_16x16x32_f16(ahi[t][0], bl0, c3, 0, 0, 0);
            c3 = __builtin_amdgcn_mfma_f32_16x16x32_f16(ahi[t][1], bl1, c3, 0, 0, 0);

            #pragma unroll
            for (int i = 0; i < 4; ++i) {
                float dot = fmaf(c2[i], 4.8828125e-4f, c1[i]);      // +C2*2^-11
                dot = fmaf(c3[i], 6.103515625e-05f, dot);           // +C3*2^-14
                float t1 = rq[t][i] + wsqv;                         // fl32 add @ ~64
                float sc = fmaf(dot, -2.0f, t1);                    // one rounding
                if (sc < best[t][i]) { best[t][i] = sc; bidx[t][i] = n; }
            }
        }
    }

    // reduce across the 16 lanes of each group (tie -> lower index)
    #pragma unroll
    for (int off = 1; off < 16; off <<= 1) {
        #pragma unroll
        for (int t = 0; t < 2; ++t)
            #pragma unroll
            for (int i = 0; i < 4; ++i) {
                float ov = __shfl_xor(best[t][i], off);
                int   oi = __shfl_xor(bidx[t][i], off);
                if (ov < best[t][i] || (ov == best[t][i] && oi < bidx[t][i])) {
                    best[t][i] = ov; bidx[t][i] = oi;
                }
            }
    }
    if (n16 == 0) {
        #pragma unroll
        for (int t = 0; t < 2; ++t)
            #pragma unroll
            for (int i = 0; i < 4; ++i) {
                bvs[wid][t * 16 + g * 4 + i] = best[t][i];
                bis[wid][t * 16 + g * 4 + i] = bidx[t][i];
            }
    }
    __syncthreads();

    // merge ct-quarters (q ascending, strict <) -> lowest code on ties
    if (tid < 32) {
        float bb = bvs[0][tid]; int ii = bis[0][tid];
        #pragma unroll
        for (int q = 1; q < 4; ++q) {
            float ov = bvs[q][tid]; int oi = bis[q][tid];
            if (ov < bb) { bb = ov; ii = oi; }
        }
        idxl[tid] = ii;
        out_idxf[rbase + tid] = (float)ii;
        atomicAdd(&counts[ii], 1.0f);
    }
    __syncthreads();

    // ---- fused quant phase ----
    float ll = 0.f;
    #pragma unroll
    for (int p = 0; p < 8; ++p) {
        int e = p * 256 + tid;
        int n = e & 31, d = e >> 5;
        float q  = w[idxl[n] * 64 + d];      // L1/L2-hot row gather
        float xv = x32[n][d];
        float dd = q - xv;
        ll += dd * dd;
        outq[b * 65536 + d * 1024 + hw0 + n] = q;
    }
    #pragma unroll
    for (int off = 32; off; off >>= 1) ll += __shfl_down(ll, off);
    if (l == 0) red[wid] = ll;
    __syncthreads();
    if (tid == 0) atomicAdd(loss, red[0] + red[1] + red[2] + red[3]);

    // dw: lane = d, one coalesced 256B atomic row per vector
    #pragma unroll
    for (int v = 0; v < 8; ++v) {
        int n = wid * 8 + v;
        atomicAdd(&dw[idxl[n] * 64 + l], x32[n][l]);
    }
}

// =====================================================================
// kernel 2 (merged finalize, round-9-verified)
// =====================================================================
__global__ __launch_bounds__(256)
void k_final(const float* __restrict__ ema_cs, const float* __restrict__ ema_w,
             const float* __restrict__ counts, const float* __restrict__ dw,
             const float* __restrict__ loss, float* __restrict__ out) {
    __shared__ float cs[1024];
    __shared__ float redA[4], redB[4];
    int tid = threadIdx.x;

    float necs[4];
    float s1 = 0.f, s2 = 0.f;
    #pragma unroll
    for (int q = 0; q < 4; ++q) {
        int j = q * 256 + tid;
        float c  = counts[j];
        float ne = 0.99f * ema_cs[j] + 0.01f * c;
        necs[q] = ne;
        float p = c * (1.0f / 32768.0f);
        s1 += ne;
        s2 += -p * logf(p + 1e-10f);
    }
    #pragma unroll
    for (int off = 32; off; off >>= 1) {
        s1 += __shfl_down(s1, off);
        s2 += __shfl_down(s2, off);
    }
    if ((tid & 63) == 0) { redA[tid >> 6] = s1; redB[tid >> 6] = s2; }
    __syncthreads();
    float ntot = redA[0] + redA[1] + redA[2] + redA[3];
    #pragma unroll
    for (int q = 0; q < 4; ++q)
        cs[q * 256 + tid] = (necs[q] + 1e-5f) / (ntot + 1024.0f * 1e-5f) * ntot;

    if (blockIdx.x == 0) {
        #pragma unroll
        for (int q = 0; q < 4; ++q) out[O_NECS + q * 256 + tid] = necs[q];
        if (tid == 0) {
            out[O_PERP] = expf(redB[0] + redB[1] + redB[2] + redB[3]);
            out[O_LOSS] = 0.25f * loss[0] * (1.0f / 2097152.0f);
        }
    }
    __syncthreads();

    int f = blockIdx.x * 256 + tid;
    int j = f >> 6;
    float ne = 0.99f * ema_w[f] + 0.01f * dw[f];
    out[O_EMAW + f] = ne;
    out[O_W + f]    = ne / cs[j];
}

// =====================================================================
extern "C" void kernel_launch(void* const* d_in, const int* in_sizes, int n_in,
                              void* d_out, int out_size, void* d_ws, size_t ws_size,
                              hipStream_t stream) {
    const float* x      = (const float*)d_in[0];
    const float* w      = (const float*)d_in[1];
    const float* ema_cs = (const float*)d_in[2];
    const float* ema_w  = (const float*)d_in[3];
    float* out = (float*)d_out;
    float* ws  = (float*)d_ws;

    _Float16* wbf  = (_Float16*)(ws + W_WBF);
    float* wsq     = ws + W_SW2;
    float* rsqb    = ws + W_RSQ;
    float* counts  = ws + W_CNT;
    float* dwb     = ws + W_DW;
    float* lossb   = ws + W_LOSS;

    k_prep <<<256,  256, 0, stream>>>(w, x, wbf, wsq, rsqb, counts);
    k_dist <<<1024, 256, 0, stream>>>(x, wbf, wsq, rsqb, w, nullptr,
                                      out + O_IDX, out + O_Q, counts, dwb, lossb);
    k_final<<<256,  256, 0, stream>>>(ema_cs, ema_w, counts, dwb, lossb, out);
}

// Round 14
// 46.748 us; speedup vs baseline: 1.7195x; 1.0605x over previous
//
#include <hip/hip_runtime.h>
#include <math.h>

typedef _Float16 half8 __attribute__((ext_vector_type(8)));
typedef _Float16 half4v __attribute__((ext_vector_type(4)));
typedef float    f32x4 __attribute__((ext_vector_type(4)));

// ---------------- output offsets (floats) ----------------
#define O_Q     0
#define O_LOSS  2097152
#define O_IDX   2097153
#define O_PERP  2129921
#define O_NECS  2129922
#define O_EMAW  2130946
#define O_W     2196482

// ---------------- workspace offsets (4-byte units) ----------------
#define W_WBF    0          // 65536 fl (=131072 halfs): B-fragments [64ct][4j][64l][8e]
#define W_SW2    65536      // 1024  wsq  (fl32 of fp64 sum)
#define W_RSQ    66560      // 32768 rsq  (fl32 of fp64 sum)
#define W_CNT    132096     // 1024  counts
#define W_DW     133120     // 65536 dw
#define W_LOSS   198656     // 1     loss
#define W_ZN     66561      // floats to zero starting at W_CNT

#define F16_MIN_NORM 6.103515625e-05f   // 2^-14

// =====================================================================
// kernel 0 (prep, grid 256): unchanged from round 10 (verified)
// =====================================================================
__global__ __launch_bounds__(256)
void k_prep(const float* __restrict__ w, const float* __restrict__ x,
            _Float16* __restrict__ wbf, float* __restrict__ wsq,
            float* __restrict__ rsq, float* __restrict__ zbase) {
    __shared__ float sh[64][65];
    int tid = threadIdx.x, blk = blockIdx.x;

    for (int z = blk * 256 + tid; z < W_ZN; z += 256 * 256) zbase[z] = 0.f;

    if (blk < 64) {
        int T  = blk * 256 + tid;           // 0..16383
        int ct = T >> 8, j = (T >> 6) & 3, l = T & 63;
        int kb = j & 1, isLo = j >> 1;
        int c  = ct * 16 + (l & 15), g = l >> 4;
        half8 o;
        #pragma unroll
        for (int e = 0; e < 8; ++e) {
            int kd = kb * 32 + g * 4 + (e & 3) + ((e >> 2) << 4);
            float wv = w[c * 64 + kd];
            _Float16 h = (fabsf(wv) >= F16_MIN_NORM) ? (_Float16)wv : (_Float16)0.f;
            if (isLo) {
                float hf = (float)h;
                o[e] = (_Float16)((wv - hf) * 16384.0f);   // lo scaled 2^14
            } else {
                o[e] = h;
            }
        }
        *(half8*)(wbf + ((ct * 4 + j) * 64 + l) * 8) = o;
    }

    if (blk < 16) {           // wsq
        int j0 = blk * 64;
        for (int p = 0; p < 16; ++p) {
            int f = p * 256 + tid;
            int j = f >> 6, d = f & 63;
            sh[j][d] = w[(j0 + j) * 64 + d];
        }
        __syncthreads();
        if (tid < 64) {
            double s = 0.0;
            #pragma unroll
            for (int d = 0; d < 64; ++d) {
                double v = (double)sh[tid][d];
                s = fma(v, v, s);
            }
            wsq[j0 + tid] = (float)s;
        }
    }

    if (blk >= 128) {         // rsq, one row per thread, d ascending
        int r = (blk - 128) * 256 + tid;
        const float* xp = x + (r >> 10) * 65536 + (r & 1023);
        double s = 0.0;
        #pragma unroll 8
        for (int d = 0; d < 64; ++d) {
            double v = (double)xp[d * 1024];
            s = fma(v, v, s);
        }
        rsq[r] = (float)s;
    }
}

// =====================================================================
// kernel 1 (fused): MFMA distances + argmin + quant/loss/counts/dw.
// Round-13 structure (grid 1024 x 4 waves; wave = ct-quarter x 2 row-
// tiles) + two latency fixes:
//  (a) explicit depth-1 B/wsq prefetch into named registers -> 4 loads
//      in flight across each MFMA block (waitcnt lands next iteration);
//  (b) quant-phase codebook gather is quarter-wave float4-coalesced into
//      LDS q32, then the loss/store loop reads LDS.
// Per-(row,ct) argmin numerics bitwise-identical to rounds 10-13.
// =====================================================================
__global__ __launch_bounds__(256, 4)
void k_dist(const float* __restrict__ x, const _Float16* __restrict__ wbf,
            const float* __restrict__ wsq, const float* __restrict__ rsq_g,
            const float* __restrict__ w,
            float* __restrict__ out_idxf,
            float* __restrict__ outq, float* __restrict__ counts,
            float* __restrict__ dw, float* __restrict__ loss) {
    __shared__ _Float16 xhi[64 * 32];
    __shared__ _Float16 xlo[64 * 32];
    __shared__ float x32[32][65];
    __shared__ float q32[32][65];
    __shared__ float bvs[4][32];
    __shared__ int   bis[4][32];
    __shared__ int   idxl[32];
    __shared__ float red[4];
    int tid = threadIdx.x;
    int rbase = blockIdx.x * 32;
    int b = rbase >> 10, hw0 = rbase & 1023;
    const float* xb = x + b * 65536 + hw0;

    // stage 32 rows -> f16 hi/lo (xlo scaled 2^11) + fp32 copy
    #pragma unroll
    for (int p = 0; p < 2; ++p) {
        int f = p * 256 + tid;
        int d = f >> 3, r4 = (f & 7) << 2;
        float4 v = *(const float4*)(xb + d * 1024 + r4);
        float vv[4] = {v.x, v.y, v.z, v.w};
        half4v h, lo;
        #pragma unroll
        for (int q = 0; q < 4; ++q) {
            float xv = vv[q];
            _Float16 hh = (fabsf(xv) >= F16_MIN_NORM) ? (_Float16)xv : (_Float16)0.f;
            h[q]  = hh;
            lo[q] = (_Float16)((xv - (float)hh) * 2048.0f);
            x32[r4 + q][d] = xv;
        }
        *(half4v*)&xhi[d * 32 + r4] = h;
        *(half4v*)&xlo[d * 32 + r4] = lo;
    }
    __syncthreads();

    int l   = tid & 63;
    int wid = tid >> 6;          // ct-quarter of this wave
    int g = l >> 4, n16 = l & 15;

    // A fragments for BOTH row-tiles (resident for the whole ct loop)
    half8 ahi[2][2], alo[2][2];
    #pragma unroll
    for (int t = 0; t < 2; ++t)
        #pragma unroll
        for (int kb = 0; kb < 2; ++kb) {
            #pragma unroll
            for (int e = 0; e < 8; ++e) {
                int kd = kb * 32 + g * 4 + (e & 3) + ((e >> 2) << 4);
                ahi[t][kb][e] = xhi[kd * 32 + t * 16 + n16];
                alo[t][kb][e] = xlo[kd * 32 + t * 16 + n16];
            }
        }

    float rq[2][4];
    #pragma unroll
    for (int t = 0; t < 2; ++t)
        #pragma unroll
        for (int i = 0; i < 4; ++i)
            rq[t][i] = rsq_g[rbase + t * 16 + g * 4 + i];

    float best[2][4];
    int   bidx[2][4];
    #pragma unroll
    for (int t = 0; t < 2; ++t)
        #pragma unroll
        for (int i = 0; i < 4; ++i) { best[t][i] = 3.4e38f; bidx[t][i] = 0; }

    const half8* wv8 = (const half8*)wbf;

    // prologue prefetch (ct = wid*16)
    const half8* wp0 = wv8 + (wid * 16) * 256 + l;
    half8 pbh0 = wp0[0], pbh1 = wp0[64], pbl0 = wp0[128], pbl1 = wp0[192];
    float pwsq = wsq[(wid * 16) * 16 + n16];

    #pragma unroll 1
    for (int c8 = 0; c8 < 16; ++c8) {
        int ct = wid * 16 + c8;
        half8 bh0 = pbh0, bh1 = pbh1, bl0 = pbl0, bl1 = pbl1;
        float wsqv = pwsq;
        if (c8 < 15) {       // prefetch next ct (wave-uniform branch)
            const half8* wn = wv8 + (ct + 1) * 256 + l;
            pbh0 = wn[0]; pbh1 = wn[64]; pbl0 = wn[128]; pbl1 = wn[192];
            pwsq = wsq[(ct + 1) * 16 + n16];
        }
        int n = ct * 16 + n16;

        #pragma unroll
        for (int t = 0; t < 2; ++t) {
            f32x4 c1 = {0.f, 0.f, 0.f, 0.f};
            f32x4 c2 = {0.f, 0.f, 0.f, 0.f};
            f32x4 c3 = {0.f, 0.f, 0.f, 0.f};
            c1 = __builtin_amdgcn_mfma_f32_16x16x32_f16(ahi[t][0], bh0, c1, 0, 0, 0);
            c1 = __builtin_amdgcn_mfma_f32_16x16x32_f16(ahi[t][1], bh1, c1, 0, 0, 0);
            c2 = __builtin_amdgcn_mfma_f32_16x16x32_f16(alo[t][0], bh0, c2, 0, 0, 0);
            c2 = __builtin_amdgcn_mfma_f32_16x16x32_f16(alo[t][1], bh1, c2, 0, 0, 0);
            c3 = __builtin_amdgcn_mfma_f32_16x16x32_f16(ahi[t][0], bl0, c3, 0, 0, 0);
            c3 = __builtin_amdgcn_mfma_f32_16x16x32_f16(ahi[t][1], bl1, c3, 0, 0, 0);

            #pragma unroll
            for (int i = 0; i < 4; ++i) {
                float dot = fmaf(c2[i], 4.8828125e-4f, c1[i]);      // +C2*2^-11
                dot = fmaf(c3[i], 6.103515625e-05f, dot);           // +C3*2^-14
                float t1 = rq[t][i] + wsqv;                         // fl32 add @ ~64
                float sc = fmaf(dot, -2.0f, t1);                    // one rounding
                if (sc < best[t][i]) { best[t][i] = sc; bidx[t][i] = n; }
            }
        }
    }

    // reduce across the 16 lanes of each group (tie -> lower index)
    #pragma unroll
    for (int off = 1; off < 16; off <<= 1) {
        #pragma unroll
        for (int t = 0; t < 2; ++t)
            #pragma unroll
            for (int i = 0; i < 4; ++i) {
                float ov = __shfl_xor(best[t][i], off);
                int   oi = __shfl_xor(bidx[t][i], off);
                if (ov < best[t][i] || (ov == best[t][i] && oi < bidx[t][i])) {
                    best[t][i] = ov; bidx[t][i] = oi;
                }
            }
    }
    if (n16 == 0) {
        #pragma unroll
        for (int t = 0; t < 2; ++t)
            #pragma unroll
            for (int i = 0; i < 4; ++i) {
                bvs[wid][t * 16 + g * 4 + i] = best[t][i];
                bis[wid][t * 16 + g * 4 + i] = bidx[t][i];
            }
    }
    __syncthreads();

    // merge ct-quarters (q ascending, strict <) -> lowest code on ties
    if (tid < 32) {
        float bb = bvs[0][tid]; int ii = bis[0][tid];
        #pragma unroll
        for (int q = 1; q < 4; ++q) {
            float ov = bvs[q][tid]; int oi = bis[q][tid];
            if (ov < bb) { bb = ov; ii = oi; }
        }
        idxl[tid] = ii;
        out_idxf[rbase + tid] = (float)ii;
        atomicAdd(&counts[ii], 1.0f);
    }
    __syncthreads();

    // ---- fused quant phase ----
    // gather codebook rows, quarter-wave float4-coalesced -> LDS
    #pragma unroll
    for (int v = 0; v < 2; ++v) {
        int n  = wid * 8 + v * 4 + (l >> 4);     // 4 rows per instr
        int d4 = (l & 15) << 2;
        *(float4*)&q32[n][d4] = *(const float4*)(w + idxl[n] * 64 + d4);
    }
    __syncthreads();

    float ll = 0.f;
    #pragma unroll
    for (int p = 0; p < 8; ++p) {
        int e = p * 256 + tid;
        int nn = e & 31, d = e >> 5;
        float q  = q32[nn][d];
        float xv = x32[nn][d];
        float dd = q - xv;
        ll += dd * dd;
        outq[b * 65536 + d * 1024 + hw0 + nn] = q;   // coalesced
    }
    #pragma unroll
    for (int off = 32; off; off >>= 1) ll += __shfl_down(ll, off);
    if (l == 0) red[wid] = ll;
    __syncthreads();
    if (tid == 0) atomicAdd(loss, red[0] + red[1] + red[2] + red[3]);

    // dw: lane = d, one coalesced 256B atomic row per vector
    #pragma unroll
    for (int v = 0; v < 8; ++v) {
        int n = wid * 8 + v;
        atomicAdd(&dw[idxl[n] * 64 + l], x32[n][l]);
    }
}

// =====================================================================
// kernel 2 (merged finalize, round-9-verified)
// =====================================================================
__global__ __launch_bounds__(256)
void k_final(const float* __restrict__ ema_cs, const float* __restrict__ ema_w,
             const float* __restrict__ counts, const float* __restrict__ dw,
             const float* __restrict__ loss, float* __restrict__ out) {
    __shared__ float cs[1024];
    __shared__ float redA[4], redB[4];
    int tid = threadIdx.x;

    float necs[4];
    float s1 = 0.f, s2 = 0.f;
    #pragma unroll
    for (int q = 0; q < 4; ++q) {
        int j = q * 256 + tid;
        float c  = counts[j];
        float ne = 0.99f * ema_cs[j] + 0.01f * c;
        necs[q] = ne;
        float p = c * (1.0f / 32768.0f);
        s1 += ne;
        s2 += -p * logf(p + 1e-10f);
    }
    #pragma unroll
    for (int off = 32; off; off >>= 1) {
        s1 += __shfl_down(s1, off);
        s2 += __shfl_down(s2, off);
    }
    if ((tid & 63) == 0) { redA[tid >> 6] = s1; redB[tid >> 6] = s2; }
    __syncthreads();
    float ntot = redA[0] + redA[1] + redA[2] + redA[3];
    #pragma unroll
    for (int q = 0; q < 4; ++q)
        cs[q * 256 + tid] = (necs[q] + 1e-5f) / (ntot + 1024.0f * 1e-5f) * ntot;

    if (blockIdx.x == 0) {
        #pragma unroll
        for (int q = 0; q < 4; ++q) out[O_NECS + q * 256 + tid] = necs[q];
        if (tid == 0) {
            out[O_PERP] = expf(redB[0] + redB[1] + redB[2] + redB[3]);
            out[O_LOSS] = 0.25f * loss[0] * (1.0f / 2097152.0f);
        }
    }
    __syncthreads();

    int f = blockIdx.x * 256 + tid;
    int j = f >> 6;
    float ne = 0.99f * ema_w[f] + 0.01f * dw[f];
    out[O_EMAW + f] = ne;
    out[O_W + f]    = ne / cs[j];
}

// =====================================================================
extern "C" void kernel_launch(void* const* d_in, const int* in_sizes, int n_in,
                              void* d_out, int out_size, void* d_ws, size_t ws_size,
                              hipStream_t stream) {
    const float* x      = (const float*)d_in[0];
    const float* w      = (const float*)d_in[1];
    const float* ema_cs = (const float*)d_in[2];
    const float* ema_w  = (const float*)d_in[3];
    float* out = (float*)d_out;
    float* ws  = (float*)d_ws;

    _Float16* wbf  = (_Float16*)(ws + W_WBF);
    float* wsq     = ws + W_SW2;
    float* rsqb    = ws + W_RSQ;
    float* counts  = ws + W_CNT;
    float* dwb     = ws + W_DW;
    float* lossb   = ws + W_LOSS;

    k_prep <<<256,  256, 0, stream>>>(w, x, wbf, wsq, rsqb, counts);
    k_dist <<<1024, 256, 0, stream>>>(x, wbf, wsq, rsqb, w,
                                      out + O_IDX, out + O_Q, counts, dwb, lossb);
    k_final<<<256,  256, 0, stream>>>(ema_cs, ema_w, counts, dwb, lossb, out);
}